// Round 15
// baseline (353.858 us; speedup 1.0000x reference)
//
#include <hip/hip_runtime.h>
#include <hip/hip_fp16.h>

#define N_NODES 100000
#define N_GRAPHS 2048
#define N_EDGES 3200000
#define NHALF 50000
#define DIM 32
#define FEAT 78
#define OUT_DIM 128
#define BN_EPS 1e-5f

#define BSHIFT 9
#define BSIZE 512
#define NB ((N_NODES + BSIZE - 1) / BSIZE)   // 196
#define CHUNK 4096
#define NSUB 4
#define NR 4                                  // node-ranges per bucket (scatter)

#define NTILES (N_NODES / 16)          // 6250
#define SBINS 64
#define AGG_BLOCKS 3128

typedef _Float16 f16x8 __attribute__((ext_vector_type(8)));
typedef float f32x4 __attribute__((ext_vector_type(4)));

// ---------------- K1: coarse bucket histogram (int4-vectorized) ----------------
__global__ __launch_bounds__(256) void bucket_hist_kernel(const int* __restrict__ dst,
                                                          int* __restrict__ bcnt) {
    __shared__ int lh[256];
    int tid = threadIdx.x;
    lh[tid] = 0;
    __syncthreads();
    const int4* d4 = (const int4*)dst;
    const int n4 = N_EDGES / 4;
    int i = blockIdx.x * blockDim.x + tid;
    int stride = gridDim.x * blockDim.x;
    for (; i < n4; i += stride) {
        int4 v = d4[i];
        atomicAdd(&lh[v.x >> BSHIFT], 1);
        atomicAdd(&lh[v.y >> BSHIFT], 1);
        atomicAdd(&lh[v.z >> BSHIFT], 1);
        atomicAdd(&lh[v.w >> BSHIFT], 1);
    }
    __syncthreads();
    if (tid < NB && lh[tid])
        atomicAdd(&bcnt[tid], lh[tid]);
}

// ---------------- K2: scan over buckets ----------------
__global__ __launch_bounds__(256) void bucket_scan_kernel(const int* __restrict__ bcnt,
                                                          int* __restrict__ bstart,
                                                          int* __restrict__ bcursor,
                                                          int* __restrict__ rowst) {
    __shared__ int sc[256];
    int tid = threadIdx.x;
    int v = (tid < NB) ? bcnt[tid] : 0;
    sc[tid] = v;
    __syncthreads();
    for (int off = 1; off < 256; off <<= 1) {
        int nv = (tid >= off) ? sc[tid - off] : 0;
        __syncthreads();
        sc[tid] += nv;
        __syncthreads();
    }
    if (tid < NB) {
        int ex = sc[tid] - v;
        bstart[tid] = ex;
        bcursor[tid] = ex;
    }
    if (tid == 0) {
        bstart[NB] = N_EDGES;
        rowst[N_NODES] = N_EDGES;
    }
}

// ---------------- K3: multisplit scatter -> packed (nloc<<17 | src), per-wave private ----
__global__ __launch_bounds__(256) void bucket_scatter_kernel(const int* __restrict__ src,
                                                             const int* __restrict__ dst,
                                                             int* __restrict__ bcursor,
                                                             int* __restrict__ epk) {
    __shared__ int lpk[CHUNK];
    __shared__ unsigned char lbkt[CHUNK];
    __shared__ int lhist[4 * 256];   // per-wave histograms
    __shared__ int lwcur[4 * 256];   // per-wave cursors
    __shared__ int sc[256];
    __shared__ int lpre[256];
    __shared__ int gbase[256];
    int tid = threadIdx.x;
    int wave = tid >> 6;
    int base = blockIdx.x * CHUNK;
    int n = N_EDGES - base; if (n > CHUNK) n = CHUNK;

    for (int j = tid; j < 4 * 256; j += 256) lhist[j] = 0;
    __syncthreads();
    for (int i = tid; i < n; i += 256)
        atomicAdd(&lhist[wave * 256 + (dst[base + i] >> BSHIFT)], 1);
    __syncthreads();
    int c0 = lhist[0 * 256 + tid];
    int c1 = lhist[1 * 256 + tid];
    int c2 = lhist[2 * 256 + tid];
    int c3 = lhist[3 * 256 + tid];
    int v = c0 + c1 + c2 + c3;
    sc[tid] = v;
    __syncthreads();
    for (int off = 1; off < 256; off <<= 1) {
        int nv = (tid >= off) ? sc[tid - off] : 0;
        __syncthreads();
        sc[tid] += nv;
        __syncthreads();
    }
    int ex = sc[tid] - v;
    lpre[tid] = ex;
    lwcur[0 * 256 + tid] = ex;
    lwcur[1 * 256 + tid] = ex + c0;
    lwcur[2 * 256 + tid] = ex + c0 + c1;
    lwcur[3 * 256 + tid] = ex + c0 + c1 + c2;
    if (tid < NB && v)
        gbase[tid] = atomicAdd(&bcursor[tid], v);
    __syncthreads();
    for (int i = tid; i < n; i += 256) {
        int d = dst[base + i];
        int s = src[base + i];
        int b = d >> BSHIFT;
        int pos = atomicAdd(&lwcur[wave * 256 + b], 1);
        lpk[pos] = ((d & (BSIZE - 1)) << 17) | s;
        lbkt[pos] = (unsigned char)b;
    }
    __syncthreads();
    for (int i = tid; i < n; i += 256) {
        int b = lbkt[i];
        int gpos = gbase[b] + (i - lpre[b]);
        epk[gpos] = lpk[i];
    }
}

// ---------------- K4a: per-(bucket,quarter) histogram, per-wave private, packed ----------
__global__ __launch_bounds__(256) void node_count_kernel(const int* __restrict__ bstart,
                                                         const int* __restrict__ epk,
                                                         int* __restrict__ qcnt) {
    __shared__ int lcnt[4 * BSIZE];
    int tid = threadIdx.x;
    int wave = tid >> 6;
    int b = blockIdx.x / NSUB;
    int qt = blockIdx.x % NSUB;
    int ss = bstart[b], se = bstart[b + 1];
    int len = se - ss;
    int qs = ss + (int)(((long long)len * qt) / NSUB);
    int qe = ss + (int)(((long long)len * (qt + 1)) / NSUB);
    for (int j = tid; j < 4 * BSIZE; j += 256) lcnt[j] = 0;
    __syncthreads();
    for (int i = qs + tid; i < qe; i += 256) {
        int pk = epk[i];
        int add = 0x10000 | (((pk & 0x1FFFF) < NHALF) ? 1 : 0);
        atomicAdd(&lcnt[wave * BSIZE + (pk >> 17)], add);
    }
    __syncthreads();
    int* qc = qcnt + (size_t)blockIdx.x * BSIZE;
    qc[tid] = lcnt[tid] + lcnt[BSIZE + tid] + lcnt[2 * BSIZE + tid] + lcnt[3 * BSIZE + tid];
    int t2 = tid + 256;
    qc[t2] = lcnt[t2] + lcnt[BSIZE + t2] + lcnt[2 * BSIZE + t2] + lcnt[3 * BSIZE + t2];
}

// ---------------- K4b: per-bucket scan -> rowst, rowmid, degf, qbase0/1 ----------------
__global__ __launch_bounds__(256) void node_scan_kernel(const int* __restrict__ bstart,
                                                        const int* __restrict__ qcnt,
                                                        int* __restrict__ qbase0,
                                                        int* __restrict__ qbase1,
                                                        int* __restrict__ rowst,
                                                        int* __restrict__ rowmid,
                                                        float* __restrict__ degf) {
    __shared__ int sc[256];
    int tid = threadIdx.x;
    int b = blockIdx.x;
    int ss = bstart[b];
    const int* qc = qcnt + (size_t)b * NSUB * BSIZE;
    int j0 = 2 * tid, j1 = 2 * tid + 1;
    int pk0[NSUB], pk1[NSUB];
    int t0 = 0, t1 = 0, m0 = 0, m1 = 0;
    #pragma unroll
    for (int q = 0; q < NSUB; ++q) {
        pk0[q] = qc[q * BSIZE + j0];
        pk1[q] = qc[q * BSIZE + j1];
        t0 += pk0[q] >> 16; m0 += pk0[q] & 0xFFFF;
        t1 += pk1[q] >> 16; m1 += pk1[q] & 0xFFFF;
    }
    int s = t0 + t1;
    sc[tid] = s;
    __syncthreads();
    for (int off = 1; off < 256; off <<= 1) {
        int nv = (tid >= off) ? sc[tid - off] : 0;
        __syncthreads();
        sc[tid] += nv;
        __syncthreads();
    }
    int ex = sc[tid] - s;
    int B0 = ss + ex;
    int B1 = B0 + t0;
    int node_base = b << BSHIFT;
    if (node_base + j0 < N_NODES) {
        rowst[node_base + j0] = B0; rowmid[node_base + j0] = B0 + m0;
        degf[node_base + j0] = (float)(t0 + 1);
    }
    if (node_base + j1 < N_NODES) {
        rowst[node_base + j1] = B1; rowmid[node_base + j1] = B1 + m1;
        degf[node_base + j1] = (float)(t1 + 1);
    }
    int r0a = B0, r0b = B0 + m0;
    int r1a = B1, r1b = B1 + m1;
    #pragma unroll
    for (int q = 0; q < NSUB; ++q) {
        int c0 = pk0[q] & 0xFFFF, ct = pk0[q] >> 16;
        qbase0[((size_t)b * NSUB + q) * BSIZE + j0] = r0a; r0a += c0;
        qbase1[((size_t)b * NSUB + q) * BSIZE + j0] = r0b; r0b += ct - c0;
        int d0c = pk1[q] & 0xFFFF, dt = pk1[q] >> 16;
        qbase0[((size_t)b * NSUB + q) * BSIZE + j1] = r1a; r1a += d0c;
        qbase1[((size_t)b * NSUB + q) * BSIZE + j1] = r1b; r1b += dt - d0c;
    }
}

// ---------------- K4c: node-range-split scatter (exclusive output lines) -> csr ----------------
__global__ __launch_bounds__(256) void node_scatter_kernel(const int* __restrict__ bstart,
                                                           const int* __restrict__ epk,
                                                           const int* __restrict__ qbase0,
                                                           const int* __restrict__ qbase1,
                                                           int* __restrict__ csr) {
    __shared__ int lcur[2 * NSUB * 128];
    int tid = threadIdx.x;
    int b = blockIdx.x / NR;
    int r = blockIdx.x % NR;
    for (int j = tid; j < NSUB * 128; j += 256) {
        int q = j >> 7, n = j & 127;
        lcur[j] = qbase0[((size_t)b * NSUB + q) * BSIZE + r * 128 + n];
        lcur[NSUB * 128 + j] = qbase1[((size_t)b * NSUB + q) * BSIZE + r * 128 + n];
    }
    __syncthreads();
    int ss = bstart[b], se = bstart[b + 1];
    int len = se - ss;
    #pragma unroll
    for (int q = 0; q < NSUB; ++q) {
        int qs = ss + (int)(((long long)len * q) / NSUB);
        int qe = ss + (int)(((long long)len * (q + 1)) / NSUB);
        for (int i = qs + tid; i < qe; i += 256) {
            int pk = epk[i];
            int nloc = pk >> 17;
            if ((nloc >> 7) == r) {
                int s = pk & 0x1FFFF;
                int h = (s >= NHALF) ? NSUB * 128 : 0;
                int pos = atomicAdd(&lcur[h + (q << 7) + (nloc & 127)], 1);
                csr[pos] = s;
            }
        }
    }
}

// ---------------- prep0: W1a fragments (K pad 96) + identity blob + cwf=0 ----------------
__global__ __launch_bounds__(1024) void prep0_kernel(const float* __restrict__ W1a,
                                                     const float* __restrict__ W1b,
                                                     __half* __restrict__ blob1,
                                                     __half* __restrict__ blob,
                                                     float* __restrict__ cwf) {
    int tid = threadIdx.x;
    for (int idx = tid; idx < 6 * 512; idx += 1024) {
        int e = idx & 7;
        int l = (idx >> 3) & 63;
        int f = idx >> 9;
        int kc = f >> 1, ct = f & 1;
        int k = kc * 32 + (l >> 4) * 8 + e;
        int col = ct * 16 + (l & 15);
        float v = (k < FEAT) ? W1a[k * DIM + col] : 0.f;
        blob1[idx] = __float2half(v);
    }
    int d = tid >> 5, k = tid & 31;
    blob[d * 32 + k] = __float2half((d == k) ? 1.f : 0.f);
    blob[1024 + d * 32 + k] = __float2half(W1b[k * 32 + d]);
    if (tid < DIM) cwf[tid] = 0.f;
}

// ---------------- transform1: MFMA x @ W1a -> table T [node][32] ----------------
__global__ __launch_bounds__(256) void transform1_kernel(const float* __restrict__ x,
                                                         const __half* __restrict__ blob1,
                                                         __half* __restrict__ T) {
    __shared__ __align__(16) _Float16 X[4][512];
    int tid = threadIdx.x;
    int wave = tid >> 6;
    int l = tid & 63;
    int d0 = l & 15, kg = l >> 4;
    int tile = blockIdx.x * 4 + wave;
    if (tile >= NTILES) return;
    int tb = tile * 16;
    const float* xr = x + (size_t)(tb + d0) * FEAT;

    f16x8 af0, af1, af2;
    #pragma unroll
    for (int j = 0; j < 4; ++j) {
        int k0 = kg * 8 + 2 * j;
        float2 v0 = *(const float2*)(xr + k0);
        float2 v1 = *(const float2*)(xr + 32 + k0);
        af0[2 * j] = (_Float16)v0.x; af0[2 * j + 1] = (_Float16)v0.y;
        af1[2 * j] = (_Float16)v1.x; af1[2 * j + 1] = (_Float16)v1.y;
        int k2 = 64 + k0;
        float2 v2 = {0.f, 0.f};
        if (k2 < FEAT) v2 = *(const float2*)(xr + k2);
        af2[2 * j] = (_Float16)v2.x; af2[2 * j + 1] = (_Float16)v2.y;
    }
    f16x8 b0 = *(const f16x8*)(blob1 + (0 * 64 + l) * 8);
    f16x8 b1 = *(const f16x8*)(blob1 + (1 * 64 + l) * 8);
    f16x8 b2 = *(const f16x8*)(blob1 + (2 * 64 + l) * 8);
    f16x8 b3 = *(const f16x8*)(blob1 + (3 * 64 + l) * 8);
    f16x8 b4 = *(const f16x8*)(blob1 + (4 * 64 + l) * 8);
    f16x8 b5 = *(const f16x8*)(blob1 + (5 * 64 + l) * 8);

    f32x4 c0 = {0.f, 0.f, 0.f, 0.f};
    f32x4 c1 = {0.f, 0.f, 0.f, 0.f};
    c0 = __builtin_amdgcn_mfma_f32_16x16x32_f16(af0, b0, c0, 0, 0, 0);
    c1 = __builtin_amdgcn_mfma_f32_16x16x32_f16(af0, b1, c1, 0, 0, 0);
    c0 = __builtin_amdgcn_mfma_f32_16x16x32_f16(af1, b2, c0, 0, 0, 0);
    c1 = __builtin_amdgcn_mfma_f32_16x16x32_f16(af1, b3, c1, 0, 0, 0);
    c0 = __builtin_amdgcn_mfma_f32_16x16x32_f16(af2, b4, c0, 0, 0, 0);
    c1 = __builtin_amdgcn_mfma_f32_16x16x32_f16(af2, b5, c1, 0, 0, 0);

    #pragma unroll
    for (int rr = 0; rr < 4; ++rr) {
        int row = kg * 4 + rr;
        X[wave][row * 32 + d0] = (_Float16)c0[rr];
        X[wave][row * 32 + d0 + 16] = (_Float16)c1[rr];
    }
    __builtin_amdgcn_wave_barrier();
    int gg = l >> 2, cq = l & 3;
    uint4 vv = *(uint4*)&X[wave][gg * 32 + cq * 8];
    *(uint4*)(T + (size_t)(tb + gg) * DIM + cq * 8) = vv;
}

// ---------------- prep: reduce stat bins + BN-fold, weights in fragment layout ----------------
__global__ __launch_bounds__(1024) void prep_kernel(const float* __restrict__ sbins,
                                                    const float* __restrict__ gamma,
                                                    const float* __restrict__ beta,
                                                    const float* __restrict__ Wa,
                                                    const float* __restrict__ Wb,
                                                    __half* __restrict__ blob,
                                                    float* __restrict__ cwf) {
    __shared__ float st[64];
    __shared__ float a[DIM], c[DIM];
    int tid = threadIdx.x;
    if (tid < 64) {
        float s = 0.f;
        for (int b = 0; b < SBINS; ++b) s += sbins[b * 64 + tid];
        st[tid] = s;
    }
    __syncthreads();
    if (tid < DIM) {
        float mu = st[tid] * (1.f / N_NODES);
        float var = st[DIM + tid] * (1.f / N_NODES) - mu * mu;
        float av = gamma[tid] * rsqrtf(var + BN_EPS);
        a[tid] = av;
        c[tid] = beta[tid] - mu * av;
    }
    __syncthreads();
    int d = tid >> 5, k = tid & 31;
    blob[d * 32 + k] = __float2half(a[k] * Wa[k * 32 + d]);
    blob[1024 + d * 32 + k] = __float2half(Wb[k * 32 + d]);
    if (tid < DIM) {
        float s = 0.f;
        for (int kk = 0; kk < DIM; ++kk)
            s += c[kk] * Wa[kk * 32 + tid];
        cwf[tid] = s;
    }
}

#define ACC8(v) do { const __half2* hp_ = (const __half2*)&(v); float2 f_; \
  f_ = __half22float2(hp_[0]); a0 += f_.x; a1 += f_.y; \
  f_ = __half22float2(hp_[1]); a2 += f_.x; a3 += f_.y; \
  f_ = __half22float2(hp_[2]); a4 += f_.x; a5 += f_.y; \
  f_ = __half22float2(hp_[3]); a6 += f_.x; a7 += f_.y; } while (0)

// ---------------- agg_pass: src-range-partitioned gather, XCD-split, full 64B rows ----------
__global__ __launch_bounds__(256) void agg_pass_kernel(const __half* __restrict__ T,
                                                       const int* __restrict__ rowst,
                                                       const int* __restrict__ rowmid,
                                                       const int* __restrict__ csr,
                                                       __half* __restrict__ P0,
                                                       __half* __restrict__ P1) {
    int b = blockIdx.x;
    int half = (b >> 2) & 1;
    int idx_in_half = (b >> 3) * 4 + (b & 3);
    int tid = threadIdx.x;
    int wave = tid >> 6;
    int l = tid & 63;
    int g = l >> 2, q = l & 3;
    int tile = idx_in_half * 4 + wave;
    if (tile >= NTILES) return;
    int node = tile * 16 + g;
    int ps, pe;
    if (half == 0) { ps = rowst[node]; pe = rowmid[node]; }
    else           { ps = rowmid[node]; pe = rowst[node + 1]; }
    float a0 = 0.f, a1 = 0.f, a2 = 0.f, a3 = 0.f,
          a4 = 0.f, a5 = 0.f, a6 = 0.f, a7 = 0.f;
    int p = ps;
    int idx[8];
    bool have = (p + 8 <= pe);
    if (have) {
        #pragma unroll
        for (int j = 0; j < 8; ++j) idx[j] = csr[p + j];
    }
    while (have) {
        uint4 v[8];
        #pragma unroll
        for (int j = 0; j < 8; ++j)
            v[j] = *(const uint4*)(T + (size_t)idx[j] * DIM + (q << 3));
        int np = p + 8;
        bool nhave = (np + 8 <= pe);
        int nidx[8];
        if (nhave) {
            #pragma unroll
            for (int j = 0; j < 8; ++j) nidx[j] = csr[np + j];
        }
        #pragma unroll
        for (int j = 0; j < 8; ++j) ACC8(v[j]);
        #pragma unroll
        for (int j = 0; j < 8; ++j) idx[j] = nidx[j];
        p = np;
        have = nhave;
    }
    if (p < pe) {
        #pragma unroll
        for (int j = 0; j < 8; ++j) {
            int ei = p + j;
            uint4 vv = {0, 0, 0, 0};
            if (ei < pe) vv = *(const uint4*)(T + (size_t)csr[ei] * DIM + (q << 3));
            ACC8(vv);
        }
    }
    int selfhalf = (node < NHALF) ? 0 : 1;
    if (selfhalf == half) {
        uint4 vs = *(const uint4*)(T + (size_t)node * DIM + (q << 3));
        ACC8(vs);
    }
    __half* P = half ? P1 : P0;
    f16x8 hv;
    hv[0] = (_Float16)a0; hv[1] = (_Float16)a1;
    hv[2] = (_Float16)a2; hv[3] = (_Float16)a3;
    hv[4] = (_Float16)a4; hv[5] = (_Float16)a5;
    hv[6] = (_Float16)a6; hv[7] = (_Float16)a7;
    *(f16x8*)(P + (size_t)node * DIM + (q << 3)) = hv;
}

// ---------------- mlp: P0+P1 -> MFMA MLP -> next table; binned BN stats ----------------
__global__ __launch_bounds__(256) void mlp_kernel(const __half* __restrict__ P0,
                                                  const __half* __restrict__ P1,
                                                  const float* __restrict__ degf,
                                                  const __half* __restrict__ blob,
                                                  const float* __restrict__ cwf,
                                                  const float* __restrict__ bias_a,
                                                  const float* __restrict__ bias_b,
                                                  __half* __restrict__ outT,
                                                  float* __restrict__ sbins) {
    __shared__ __align__(16) _Float16 X[4][512];
    int tid = threadIdx.x;
    int wave = tid >> 6;
    int l = tid & 63;
    int d0 = l & 15, kg = l >> 4;
    int tile = blockIdx.x * 4 + wave;
    if (tile >= NTILES) return;
    int tb = tile * 16;

    f16x8 v0 = *(const f16x8*)(P0 + (size_t)(tb + d0) * DIM + kg * 8);
    f16x8 v1 = *(const f16x8*)(P1 + (size_t)(tb + d0) * DIM + kg * 8);
    f16x8 af = v0 + v1;
    f16x8 bA0 = *(const f16x8*)(blob + d0 * 32 + kg * 8);
    f16x8 bA1 = *(const f16x8*)(blob + (d0 + 16) * 32 + kg * 8);
    f16x8 bB0 = *(const f16x8*)(blob + 1024 + d0 * 32 + kg * 8);
    f16x8 bB1 = *(const f16x8*)(blob + 1024 + (d0 + 16) * 32 + kg * 8);
    f32x4 degv = *(const f32x4*)(degf + tb + kg * 4);
    float cw0 = cwf[d0], cw1 = cwf[d0 + 16];
    float ba0 = bias_a[d0], ba1 = bias_a[d0 + 16];
    float bb0 = bias_b[d0], bb1 = bias_b[d0 + 16];

    f32x4 c0 = {ba0, ba0, ba0, ba0};
    f32x4 c1 = {ba1, ba1, ba1, ba1};
    c0 = __builtin_amdgcn_mfma_f32_16x16x32_f16(af, bA0, c0, 0, 0, 0);
    c1 = __builtin_amdgcn_mfma_f32_16x16x32_f16(af, bA1, c1, 0, 0, 0);
    #pragma unroll
    for (int rr = 0; rr < 4; ++rr) {
        float w0 = fmaxf(c0[rr] + degv[rr] * cw0, 0.f);
        float w1 = fmaxf(c1[rr] + degv[rr] * cw1, 0.f);
        int row = kg * 4 + rr;
        X[wave][row * 32 + d0] = (_Float16)w0;
        X[wave][row * 32 + d0 + 16] = (_Float16)w1;
    }
    __builtin_amdgcn_wave_barrier();
    f16x8 af2 = *(f16x8*)&X[wave][d0 * 32 + kg * 8];
    __builtin_amdgcn_wave_barrier();

    f32x4 e0 = {bb0, bb0, bb0, bb0};
    f32x4 e1 = {bb1, bb1, bb1, bb1};
    e0 = __builtin_amdgcn_mfma_f32_16x16x32_f16(af2, bB0, e0, 0, 0, 0);
    e1 = __builtin_amdgcn_mfma_f32_16x16x32_f16(af2, bB1, e1, 0, 0, 0);
    float s0 = 0.f, ss0 = 0.f, s1 = 0.f, ss1 = 0.f;
    #pragma unroll
    for (int rr = 0; rr < 4; ++rr) {
        float y0 = fmaxf(e0[rr], 0.f);
        float y1 = fmaxf(e1[rr], 0.f);
        s0 += y0; ss0 += y0 * y0;
        s1 += y1; ss1 += y1 * y1;
        int row = kg * 4 + rr;
        X[wave][row * 32 + d0] = (_Float16)y0;
        X[wave][row * 32 + d0 + 16] = (_Float16)y1;
    }
    __builtin_amdgcn_wave_barrier();
    {
        int gg = l >> 2, c = l & 3;
        uint4 vv = *(uint4*)&X[wave][gg * 32 + c * 8];
        *(uint4*)(outT + (size_t)(tb + gg) * DIM + c * 8) = vv;
    }
    s0 += __shfl_xor(s0, 16); s0 += __shfl_xor(s0, 32);
    ss0 += __shfl_xor(ss0, 16); ss0 += __shfl_xor(ss0, 32);
    s1 += __shfl_xor(s1, 16); s1 += __shfl_xor(s1, 32);
    ss1 += __shfl_xor(ss1, 16); ss1 += __shfl_xor(ss1, 32);
    if (kg == 0) {
        float* sb = sbins + ((blockIdx.x * 4 + wave) & (SBINS - 1)) * 64;
        atomicAdd(&sb[d0], s0);
        atomicAdd(&sb[DIM + d0], ss0);
        atomicAdd(&sb[d0 + 16], s1);
        atomicAdd(&sb[DIM + d0 + 16], ss1);
    }
}

// ---------------- final BN + global_add_pool (run-length, batch sorted) ----------------
#define POOL_BLOCKS 512
__global__ __launch_bounds__(256) void bn_pool_kernel(const __half* __restrict__ h,
                                                      const float* __restrict__ sbins,
                                                      const float* __restrict__ gamma,
                                                      const float* __restrict__ beta,
                                                      const int* __restrict__ batch,
                                                      float* __restrict__ pooled) {
    __shared__ float st[64];
    int tid = threadIdx.x;
    if (tid < 64) {
        float s = 0.f;
        for (int b = 0; b < SBINS; ++b) s += sbins[b * 64 + tid];
        st[tid] = s;
    }
    __syncthreads();
    int lane = tid & 31;
    int group = tid >> 5;
    float mu = st[lane] * (1.f / N_NODES);
    float var = st[DIM + lane] * (1.f / N_NODES) - mu * mu;
    float inv = rsqrtf(var + BN_EPS);
    float a = gamma[lane] * inv;
    float c = beta[lane] - mu * a;
    const int ngroups = POOL_BLOCKS * 8;
    const int chunk = (N_NODES + ngroups - 1) / ngroups;
    int g = blockIdx.x * 8 + group;
    int start = g * chunk;
    if (start >= N_NODES) return;
    int end = start + chunk; if (end > N_NODES) end = N_NODES;
    int cur = batch[start];
    float s = 0.f;
    for (int node = start; node < end; ++node) {
        float v = __half2float(h[(size_t)node * DIM + lane]) * a + c;
        int bg = batch[node];
        if (bg != cur) {
            atomicAdd(&pooled[cur * DIM + lane], s);
            s = 0.f;
            cur = bg;
        }
        s += v;
    }
    atomicAdd(&pooled[cur * DIM + lane], s);
}

// ---------------- out = relu(pooled @ Wfc + bfc) ----------------
__global__ __launch_bounds__(256) void fc_kernel(const float* __restrict__ pooled,
                                                 const float* __restrict__ Wfc,
                                                 const float* __restrict__ bfc,
                                                 float* __restrict__ out) {
    __shared__ float Wl[DIM * OUT_DIM];
    for (int i = threadIdx.x; i < DIM * OUT_DIM; i += blockDim.x) Wl[i] = Wfc[i];
    __syncthreads();
    int idx = blockIdx.x * blockDim.x + threadIdx.x;
    int stride = gridDim.x * blockDim.x;
    for (; idx < N_GRAPHS * OUT_DIM; idx += stride) {
        int g = idx >> 7;
        int o = idx & 127;
        float acc = bfc[o];
        #pragma unroll
        for (int k = 0; k < DIM; ++k)
            acc += pooled[g * DIM + k] * Wl[k * OUT_DIM + o];
        out[idx] = fmaxf(acc, 0.f);
    }
}

extern "C" void kernel_launch(void* const* d_in, const int* in_sizes, int n_in,
                              void* d_out, int out_size, void* d_ws, size_t ws_size,
                              hipStream_t stream) {
    const float* x   = (const float*)d_in[0];
    const int* eidx  = (const int*)d_in[1];
    const int* src   = eidx;
    const int* dst   = eidx + N_EDGES;
    const int* batch = (const int*)d_in[2];
    const float* W1a = (const float*)d_in[3];
    const float* b1a = (const float*)d_in[4];
    const float* W1b = (const float*)d_in[5];
    const float* b1b = (const float*)d_in[6];
    const float* Wa  = (const float*)d_in[7];
    const float* ba  = (const float*)d_in[8];
    const float* Wb  = (const float*)d_in[9];
    const float* bb  = (const float*)d_in[10];
    const float* gamma = (const float*)d_in[11];
    const float* beta  = (const float*)d_in[12];
    const float* Wfc = (const float*)d_in[13];
    const float* bfc = (const float*)d_in[14];
    float* out = (float*)d_out;

    const size_t TSZ = (size_t)N_NODES * DIM;                // 3.2M halfs = 6.4MB
    __half* TA = (__half*)d_ws;                              // 6.4MB
    __half* TB = TA + TSZ;                                   // 6.4MB
    __half* P0 = TB + TSZ;                                   // 6.4MB
    __half* P1 = P0 + TSZ;                                   // 6.4MB
    float* degf   = (float*)(P1 + TSZ);                      // 400KB
    float* sbins  = degf + N_NODES;                          // 5 * SBINS * 64
    float* pooled = sbins + 5 * SBINS * 64;                  // 256KB (contiguous after sbins)
    float* cwf    = pooled + N_GRAPHS * DIM;                 // 5*32
    __half* blobs = (__half*)(cwf + 5 * 32);                 // 5*2048 halfs
    __half* blob1 = blobs + 5 * 2048;                        // 3072 halfs
    int* csr      = (int*)(blob1 + 6 * 512);                 // 12.8MB
    int* rowst    = csr + N_EDGES;                           // N_NODES+1
    int* rowmid   = rowst + N_NODES + 1;                     // N_NODES
    int* bcnt     = rowmid + N_NODES;
    int* bstart   = bcnt + 256;
    int* bcursor  = bstart + NB + 1;
    int* qcnt     = bcursor + 256;                           // NB*NSUB*BSIZE (packed)

    // aliases (dead before hosts' first use)
    int* epk             = (int*)TA;              // 12.8MB packed edges over TA+TB
    int* qbase0          = (int*)P1;              // 1.6MB in P1
    int* qbase1          = qbase0 + NB * NSUB * BSIZE;  // 1.6MB in P1

    hipMemsetAsync(bcnt, 0, 256 * sizeof(int), stream);
    hipMemsetAsync(sbins, 0, (5 * SBINS * 64 + N_GRAPHS * DIM) * sizeof(float), stream);

    bucket_hist_kernel<<<1024, 256, 0, stream>>>(dst, bcnt);
    bucket_scan_kernel<<<1, 256, 0, stream>>>(bcnt, bstart, bcursor, rowst);
    bucket_scatter_kernel<<<(N_EDGES + CHUNK - 1) / CHUNK, 256, 0, stream>>>(src, dst, bcursor, epk);
    node_count_kernel<<<NB * NSUB, 256, 0, stream>>>(bstart, epk, qcnt);
    node_scan_kernel<<<NB, 256, 0, stream>>>(bstart, qcnt, qbase0, qbase1, rowst, rowmid, degf);
    node_scatter_kernel<<<NB * NR, 256, 0, stream>>>(bstart, epk, qbase0, qbase1, csr);

    prep0_kernel<<<1, 1024, 0, stream>>>(W1a, W1b, blob1, blobs, cwf);
    transform1_kernel<<<(NTILES + 3) / 4, 256, 0, stream>>>(x, blob1, TA);

    const __half* in = TA;
    __half* o = TB;

    // layer 1
    agg_pass_kernel<<<AGG_BLOCKS, 256, 0, stream>>>(in, rowst, rowmid, csr, P0, P1);
    mlp_kernel<<<(NTILES + 3) / 4, 256, 0, stream>>>(P0, P1, degf, blobs, cwf, b1a, b1b, o, sbins);
    { const __half* t = in; in = o; o = (__half*)t; }

    for (int i = 0; i < 4; ++i) {
        __half* blob_i = blobs + (i + 1) * 2048;
        float* cwf_i = cwf + (i + 1) * 32;
        prep_kernel<<<1, 1024, 0, stream>>>(sbins + i * SBINS * 64, gamma + i * DIM, beta + i * DIM,
                                            Wa + i * DIM * DIM, Wb + i * DIM * DIM, blob_i, cwf_i);
        agg_pass_kernel<<<AGG_BLOCKS, 256, 0, stream>>>(in, rowst, rowmid, csr, P0, P1);
        mlp_kernel<<<(NTILES + 3) / 4, 256, 0, stream>>>(P0, P1, degf, blob_i, cwf_i,
                                                         ba + i * DIM, bb + i * DIM, o,
                                                         sbins + (i + 1) * SBINS * 64);
        { const __half* t = in; in = o; o = (__half*)t; }
    }

    bn_pool_kernel<<<POOL_BLOCKS, 256, 0, stream>>>(in, sbins + 4 * SBINS * 64,
                                                    gamma + 4 * DIM, beta + 4 * DIM, batch, pooled);
    fc_kernel<<<1024, 256, 0, stream>>>(pooled, Wfc, bfc, out);
}

// Round 16
// 309.223 us; speedup vs baseline: 1.1443x; 1.1443x over previous
//
#include <hip/hip_runtime.h>
#include <hip/hip_fp16.h>

#define N_NODES 100000
#define N_GRAPHS 2048
#define N_EDGES 3200000
#define NHALF 50000
#define DIM 32
#define FEAT 78
#define OUT_DIM 128
#define BN_EPS 1e-5f

#define BSHIFT 9
#define BSIZE 512
#define NB ((N_NODES + BSIZE - 1) / BSIZE)   // 196
#define CHUNK 4096
#define NCH ((N_EDGES + CHUNK - 1) / CHUNK)  // 782
#define NSUB 4
#define NR 4

#define NTILES (N_NODES / 16)          // 6250
#define SBINS 64
#define AGG_BLOCKS 3128

typedef _Float16 f16x8 __attribute__((ext_vector_type(8)));
typedef float f32x4 __attribute__((ext_vector_type(4)));

// ---------------- K1: per-chunk bucket histogram (non-atomic output) ----------------
__global__ __launch_bounds__(256) void bucket_hist_kernel(const int* __restrict__ dst,
                                                          int* __restrict__ bhist) {
    __shared__ int lh[4 * 256];
    int tid = threadIdx.x;
    int wave = tid >> 6;
    for (int j = tid; j < 4 * 256; j += 256) lh[j] = 0;
    __syncthreads();
    int base = blockIdx.x * CHUNK;
    int n = N_EDGES - base; if (n > CHUNK) n = CHUNK;
    const int4* d4 = (const int4*)(dst + base);
    for (int i = tid; i < (n >> 2); i += 256) {
        int4 v = d4[i];
        atomicAdd(&lh[wave * 256 + (v.x >> BSHIFT)], 1);
        atomicAdd(&lh[wave * 256 + (v.y >> BSHIFT)], 1);
        atomicAdd(&lh[wave * 256 + (v.z >> BSHIFT)], 1);
        atomicAdd(&lh[wave * 256 + (v.w >> BSHIFT)], 1);
    }
    __syncthreads();
    bhist[(size_t)blockIdx.x * 256 + tid] =
        lh[tid] + lh[256 + tid] + lh[512 + tid] + lh[768 + tid];
}

// ---------------- K1b: per-bucket column scan over chunks (in-place prefix) ----------------
__global__ __launch_bounds__(256) void col_scan_kernel(int* __restrict__ bhist,
                                                       int* __restrict__ bcnt) {
    __shared__ int sc[256];
    int b = blockIdx.x;
    int tid = threadIdx.x;
    const int per = (NCH + 255) / 256;   // 4
    int vals[(NCH + 255) / 256];
    int s = 0;
    #pragma unroll
    for (int k = 0; k < per; ++k) {
        int i = tid * per + k;
        int v = (i < NCH) ? bhist[(size_t)i * 256 + b] : 0;
        vals[k] = v; s += v;
    }
    sc[tid] = s;
    __syncthreads();
    for (int off = 1; off < 256; off <<= 1) {
        int nv = (tid >= off) ? sc[tid - off] : 0;
        __syncthreads();
        sc[tid] += nv;
        __syncthreads();
    }
    int run = sc[tid] - s;
    #pragma unroll
    for (int k = 0; k < per; ++k) {
        int i = tid * per + k;
        if (i < NCH) { int v = vals[k]; bhist[(size_t)i * 256 + b] = run; run += v; }
    }
    if (tid == 255) bcnt[b] = sc[255];
}

// ---------------- K2: scan over buckets ----------------
__global__ __launch_bounds__(256) void bucket_scan_kernel(const int* __restrict__ bcnt,
                                                          int* __restrict__ bstart,
                                                          int* __restrict__ rowst) {
    __shared__ int sc[256];
    int tid = threadIdx.x;
    int v = (tid < NB) ? bcnt[tid] : 0;
    sc[tid] = v;
    __syncthreads();
    for (int off = 1; off < 256; off <<= 1) {
        int nv = (tid >= off) ? sc[tid - off] : 0;
        __syncthreads();
        sc[tid] += nv;
        __syncthreads();
    }
    if (tid < NB) bstart[tid] = sc[tid] - v;
    if (tid == 0) {
        bstart[NB] = N_EDGES;
        rowst[N_NODES] = N_EDGES;
    }
}

// ---------------- K3: multisplit scatter, atomic-free global base ----------------
__global__ __launch_bounds__(256) void bucket_scatter_kernel(const int* __restrict__ src,
                                                             const int* __restrict__ dst,
                                                             const int* __restrict__ bstart,
                                                             const int* __restrict__ bhist,
                                                             int* __restrict__ epk) {
    __shared__ int lpk[CHUNK];
    __shared__ unsigned char lbkt[CHUNK];
    __shared__ int lhist[4 * 256];
    __shared__ int lwcur[4 * 256];
    __shared__ int sc[256];
    __shared__ int lpre[256];
    __shared__ int gbase[256];
    int tid = threadIdx.x;
    int wave = tid >> 6;
    int base = blockIdx.x * CHUNK;
    int n = N_EDGES - base; if (n > CHUNK) n = CHUNK;

    for (int j = tid; j < 4 * 256; j += 256) lhist[j] = 0;
    gbase[tid] = ((tid < NB) ? bstart[tid] : 0) + bhist[(size_t)blockIdx.x * 256 + tid];
    __syncthreads();
    for (int i = tid; i < n; i += 256)
        atomicAdd(&lhist[wave * 256 + (dst[base + i] >> BSHIFT)], 1);
    __syncthreads();
    int c0 = lhist[0 * 256 + tid];
    int c1 = lhist[1 * 256 + tid];
    int c2 = lhist[2 * 256 + tid];
    int c3 = lhist[3 * 256 + tid];
    int v = c0 + c1 + c2 + c3;
    sc[tid] = v;
    __syncthreads();
    for (int off = 1; off < 256; off <<= 1) {
        int nv = (tid >= off) ? sc[tid - off] : 0;
        __syncthreads();
        sc[tid] += nv;
        __syncthreads();
    }
    int ex = sc[tid] - v;
    lpre[tid] = ex;
    lwcur[0 * 256 + tid] = ex;
    lwcur[1 * 256 + tid] = ex + c0;
    lwcur[2 * 256 + tid] = ex + c0 + c1;
    lwcur[3 * 256 + tid] = ex + c0 + c1 + c2;
    __syncthreads();
    for (int i = tid; i < n; i += 256) {
        int d = dst[base + i];
        int s = src[base + i];
        int b = d >> BSHIFT;
        int pos = atomicAdd(&lwcur[wave * 256 + b], 1);
        lpk[pos] = ((d & (BSIZE - 1)) << 17) | s;
        lbkt[pos] = (unsigned char)b;
    }
    __syncthreads();
    for (int i = tid; i < n; i += 256) {
        int b = lbkt[i];
        int gpos = gbase[b] + (i - lpre[b]);
        epk[gpos] = lpk[i];
    }
}

// ---------------- K4a: per-(bucket,quarter) histogram, per-wave private, packed ----------
__global__ __launch_bounds__(256) void node_count_kernel(const int* __restrict__ bstart,
                                                         const int* __restrict__ epk,
                                                         int* __restrict__ qcnt) {
    __shared__ int lcnt[4 * BSIZE];
    int tid = threadIdx.x;
    int wave = tid >> 6;
    int b = blockIdx.x / NSUB;
    int qt = blockIdx.x % NSUB;
    int ss = bstart[b], se = bstart[b + 1];
    int len = se - ss;
    int qs = ss + (int)(((long long)len * qt) / NSUB);
    int qe = ss + (int)(((long long)len * (qt + 1)) / NSUB);
    for (int j = tid; j < 4 * BSIZE; j += 256) lcnt[j] = 0;
    __syncthreads();
    for (int i = qs + tid; i < qe; i += 256) {
        int pk = epk[i];
        int add = 0x10000 | (((pk & 0x1FFFF) < NHALF) ? 1 : 0);
        atomicAdd(&lcnt[wave * BSIZE + (pk >> 17)], add);
    }
    __syncthreads();
    int* qc = qcnt + (size_t)blockIdx.x * BSIZE;
    qc[tid] = lcnt[tid] + lcnt[BSIZE + tid] + lcnt[2 * BSIZE + tid] + lcnt[3 * BSIZE + tid];
    int t2 = tid + 256;
    qc[t2] = lcnt[t2] + lcnt[BSIZE + t2] + lcnt[2 * BSIZE + t2] + lcnt[3 * BSIZE + t2];
}

// ---------------- K4b: per-bucket scan -> rowst, rowmid, degf, qbase0/1 ----------------
__global__ __launch_bounds__(256) void node_scan_kernel(const int* __restrict__ bstart,
                                                        const int* __restrict__ qcnt,
                                                        int* __restrict__ qbase0,
                                                        int* __restrict__ qbase1,
                                                        int* __restrict__ rowst,
                                                        int* __restrict__ rowmid,
                                                        float* __restrict__ degf) {
    __shared__ int sc[256];
    int tid = threadIdx.x;
    int b = blockIdx.x;
    int ss = bstart[b];
    const int* qc = qcnt + (size_t)b * NSUB * BSIZE;
    int j0 = 2 * tid, j1 = 2 * tid + 1;
    int pk0[NSUB], pk1[NSUB];
    int t0 = 0, t1 = 0, m0 = 0, m1 = 0;
    #pragma unroll
    for (int q = 0; q < NSUB; ++q) {
        pk0[q] = qc[q * BSIZE + j0];
        pk1[q] = qc[q * BSIZE + j1];
        t0 += pk0[q] >> 16; m0 += pk0[q] & 0xFFFF;
        t1 += pk1[q] >> 16; m1 += pk1[q] & 0xFFFF;
    }
    int s = t0 + t1;
    sc[tid] = s;
    __syncthreads();
    for (int off = 1; off < 256; off <<= 1) {
        int nv = (tid >= off) ? sc[tid - off] : 0;
        __syncthreads();
        sc[tid] += nv;
        __syncthreads();
    }
    int ex = sc[tid] - s;
    int B0 = ss + ex;
    int B1 = B0 + t0;
    int node_base = b << BSHIFT;
    if (node_base + j0 < N_NODES) {
        rowst[node_base + j0] = B0; rowmid[node_base + j0] = B0 + m0;
        degf[node_base + j0] = (float)(t0 + 1);
    }
    if (node_base + j1 < N_NODES) {
        rowst[node_base + j1] = B1; rowmid[node_base + j1] = B1 + m1;
        degf[node_base + j1] = (float)(t1 + 1);
    }
    int r0a = B0, r0b = B0 + m0;
    int r1a = B1, r1b = B1 + m1;
    #pragma unroll
    for (int q = 0; q < NSUB; ++q) {
        int c0 = pk0[q] & 0xFFFF, ct = pk0[q] >> 16;
        qbase0[((size_t)b * NSUB + q) * BSIZE + j0] = r0a; r0a += c0;
        qbase1[((size_t)b * NSUB + q) * BSIZE + j0] = r0b; r0b += ct - c0;
        int d0c = pk1[q] & 0xFFFF, dt = pk1[q] >> 16;
        qbase0[((size_t)b * NSUB + q) * BSIZE + j1] = r1a; r1a += d0c;
        qbase1[((size_t)b * NSUB + q) * BSIZE + j1] = r1b; r1b += dt - d0c;
    }
}

// ---------------- K4c: node-range-split scatter (exclusive output lines) -> csr ----------------
__global__ __launch_bounds__(256) void node_scatter_kernel(const int* __restrict__ bstart,
                                                           const int* __restrict__ epk,
                                                           const int* __restrict__ qbase0,
                                                           const int* __restrict__ qbase1,
                                                           int* __restrict__ csr) {
    __shared__ int lcur[2 * NSUB * 128];
    int tid = threadIdx.x;
    int b = blockIdx.x / NR;
    int r = blockIdx.x % NR;
    for (int j = tid; j < NSUB * 128; j += 256) {
        int q = j >> 7, n = j & 127;
        lcur[j] = qbase0[((size_t)b * NSUB + q) * BSIZE + r * 128 + n];
        lcur[NSUB * 128 + j] = qbase1[((size_t)b * NSUB + q) * BSIZE + r * 128 + n];
    }
    __syncthreads();
    int ss = bstart[b], se = bstart[b + 1];
    int len = se - ss;
    #pragma unroll
    for (int q = 0; q < NSUB; ++q) {
        int qs = ss + (int)(((long long)len * q) / NSUB);
        int qe = ss + (int)(((long long)len * (q + 1)) / NSUB);
        for (int i = qs + tid; i < qe; i += 256) {
            int pk = epk[i];
            int nloc = pk >> 17;
            if ((nloc >> 7) == r) {
                int s = pk & 0x1FFFF;
                int h = (s >= NHALF) ? NSUB * 128 : 0;
                int pos = atomicAdd(&lcur[h + (q << 7) + (nloc & 127)], 1);
                csr[pos] = s;
            }
        }
    }
}

// ---------------- prep0: W1a fragments (K pad 96) + identity blob + cwf=0 ----------------
__global__ __launch_bounds__(1024) void prep0_kernel(const float* __restrict__ W1a,
                                                     const float* __restrict__ W1b,
                                                     __half* __restrict__ blob1,
                                                     __half* __restrict__ blob,
                                                     float* __restrict__ cwf) {
    int tid = threadIdx.x;
    for (int idx = tid; idx < 6 * 512; idx += 1024) {
        int e = idx & 7;
        int l = (idx >> 3) & 63;
        int f = idx >> 9;
        int kc = f >> 1, ct = f & 1;
        int k = kc * 32 + (l >> 4) * 8 + e;
        int col = ct * 16 + (l & 15);
        float v = (k < FEAT) ? W1a[k * DIM + col] : 0.f;
        blob1[idx] = __float2half(v);
    }
    int d = tid >> 5, k = tid & 31;
    blob[d * 32 + k] = __float2half((d == k) ? 1.f : 0.f);
    blob[1024 + d * 32 + k] = __float2half(W1b[k * 32 + d]);
    if (tid < DIM) cwf[tid] = 0.f;
}

// ---------------- transform1: MFMA x @ W1a -> table T [node][32] ----------------
__global__ __launch_bounds__(256) void transform1_kernel(const float* __restrict__ x,
                                                         const __half* __restrict__ blob1,
                                                         __half* __restrict__ T) {
    __shared__ __align__(16) _Float16 X[4][512];
    int tid = threadIdx.x;
    int wave = tid >> 6;
    int l = tid & 63;
    int d0 = l & 15, kg = l >> 4;
    int tile = blockIdx.x * 4 + wave;
    if (tile >= NTILES) return;
    int tb = tile * 16;
    const float* xr = x + (size_t)(tb + d0) * FEAT;

    f16x8 af0, af1, af2;
    #pragma unroll
    for (int j = 0; j < 4; ++j) {
        int k0 = kg * 8 + 2 * j;
        float2 v0 = *(const float2*)(xr + k0);
        float2 v1 = *(const float2*)(xr + 32 + k0);
        af0[2 * j] = (_Float16)v0.x; af0[2 * j + 1] = (_Float16)v0.y;
        af1[2 * j] = (_Float16)v1.x; af1[2 * j + 1] = (_Float16)v1.y;
        int k2 = 64 + k0;
        float2 v2 = {0.f, 0.f};
        if (k2 < FEAT) v2 = *(const float2*)(xr + k2);
        af2[2 * j] = (_Float16)v2.x; af2[2 * j + 1] = (_Float16)v2.y;
    }
    f16x8 b0 = *(const f16x8*)(blob1 + (0 * 64 + l) * 8);
    f16x8 b1 = *(const f16x8*)(blob1 + (1 * 64 + l) * 8);
    f16x8 b2 = *(const f16x8*)(blob1 + (2 * 64 + l) * 8);
    f16x8 b3 = *(const f16x8*)(blob1 + (3 * 64 + l) * 8);
    f16x8 b4 = *(const f16x8*)(blob1 + (4 * 64 + l) * 8);
    f16x8 b5 = *(const f16x8*)(blob1 + (5 * 64 + l) * 8);

    f32x4 c0 = {0.f, 0.f, 0.f, 0.f};
    f32x4 c1 = {0.f, 0.f, 0.f, 0.f};
    c0 = __builtin_amdgcn_mfma_f32_16x16x32_f16(af0, b0, c0, 0, 0, 0);
    c1 = __builtin_amdgcn_mfma_f32_16x16x32_f16(af0, b1, c1, 0, 0, 0);
    c0 = __builtin_amdgcn_mfma_f32_16x16x32_f16(af1, b2, c0, 0, 0, 0);
    c1 = __builtin_amdgcn_mfma_f32_16x16x32_f16(af1, b3, c1, 0, 0, 0);
    c0 = __builtin_amdgcn_mfma_f32_16x16x32_f16(af2, b4, c0, 0, 0, 0);
    c1 = __builtin_amdgcn_mfma_f32_16x16x32_f16(af2, b5, c1, 0, 0, 0);

    #pragma unroll
    for (int rr = 0; rr < 4; ++rr) {
        int row = kg * 4 + rr;
        X[wave][row * 32 + d0] = (_Float16)c0[rr];
        X[wave][row * 32 + d0 + 16] = (_Float16)c1[rr];
    }
    __builtin_amdgcn_wave_barrier();
    int gg = l >> 2, cq = l & 3;
    uint4 vv = *(uint4*)&X[wave][gg * 32 + cq * 8];
    *(uint4*)(T + (size_t)(tb + gg) * DIM + cq * 8) = vv;
}

// ---------------- prep: reduce stat bins + BN-fold, weights in fragment layout ----------------
__global__ __launch_bounds__(1024) void prep_kernel(const float* __restrict__ sbins,
                                                    const float* __restrict__ gamma,
                                                    const float* __restrict__ beta,
                                                    const float* __restrict__ Wa,
                                                    const float* __restrict__ Wb,
                                                    __half* __restrict__ blob,
                                                    float* __restrict__ cwf) {
    __shared__ float st[64];
    __shared__ float a[DIM], c[DIM];
    int tid = threadIdx.x;
    if (tid < 64) {
        float s = 0.f;
        for (int b = 0; b < SBINS; ++b) s += sbins[b * 64 + tid];
        st[tid] = s;
    }
    __syncthreads();
    if (tid < DIM) {
        float mu = st[tid] * (1.f / N_NODES);
        float var = st[DIM + tid] * (1.f / N_NODES) - mu * mu;
        float av = gamma[tid] * rsqrtf(var + BN_EPS);
        a[tid] = av;
        c[tid] = beta[tid] - mu * av;
    }
    __syncthreads();
    int d = tid >> 5, k = tid & 31;
    blob[d * 32 + k] = __float2half(a[k] * Wa[k * 32 + d]);
    blob[1024 + d * 32 + k] = __float2half(Wb[k * 32 + d]);
    if (tid < DIM) {
        float s = 0.f;
        for (int kk = 0; kk < DIM; ++kk)
            s += c[kk] * Wa[kk * 32 + tid];
        cwf[tid] = s;
    }
}

#define ACC8(v) do { const __half2* hp_ = (const __half2*)&(v); float2 f_; \
  f_ = __half22float2(hp_[0]); a0 += f_.x; a1 += f_.y; \
  f_ = __half22float2(hp_[1]); a2 += f_.x; a3 += f_.y; \
  f_ = __half22float2(hp_[2]); a4 += f_.x; a5 += f_.y; \
  f_ = __half22float2(hp_[3]); a6 += f_.x; a7 += f_.y; } while (0)

// ---------------- agg_pass: src-range-partitioned gather, XCD-split, full 64B rows ----------
__global__ __launch_bounds__(256) void agg_pass_kernel(const __half* __restrict__ T,
                                                       const int* __restrict__ rowst,
                                                       const int* __restrict__ rowmid,
                                                       const int* __restrict__ csr,
                                                       __half* __restrict__ P0,
                                                       __half* __restrict__ P1) {
    int b = blockIdx.x;
    int half = (b >> 2) & 1;
    int idx_in_half = (b >> 3) * 4 + (b & 3);
    int tid = threadIdx.x;
    int wave = tid >> 6;
    int l = tid & 63;
    int g = l >> 2, q = l & 3;
    int tile = idx_in_half * 4 + wave;
    if (tile >= NTILES) return;
    int node = tile * 16 + g;
    int ps, pe;
    if (half == 0) { ps = rowst[node]; pe = rowmid[node]; }
    else           { ps = rowmid[node]; pe = rowst[node + 1]; }
    float a0 = 0.f, a1 = 0.f, a2 = 0.f, a3 = 0.f,
          a4 = 0.f, a5 = 0.f, a6 = 0.f, a7 = 0.f;
    int p = ps;
    int idx[8];
    bool have = (p + 8 <= pe);
    if (have) {
        #pragma unroll
        for (int j = 0; j < 8; ++j) idx[j] = csr[p + j];
    }
    while (have) {
        uint4 v[8];
        #pragma unroll
        for (int j = 0; j < 8; ++j)
            v[j] = *(const uint4*)(T + (size_t)idx[j] * DIM + (q << 3));
        int np = p + 8;
        bool nhave = (np + 8 <= pe);
        int nidx[8];
        if (nhave) {
            #pragma unroll
            for (int j = 0; j < 8; ++j) nidx[j] = csr[np + j];
        }
        #pragma unroll
        for (int j = 0; j < 8; ++j) ACC8(v[j]);
        #pragma unroll
        for (int j = 0; j < 8; ++j) idx[j] = nidx[j];
        p = np;
        have = nhave;
    }
    if (p < pe) {
        #pragma unroll
        for (int j = 0; j < 8; ++j) {
            int ei = p + j;
            uint4 vv = {0, 0, 0, 0};
            if (ei < pe) vv = *(const uint4*)(T + (size_t)csr[ei] * DIM + (q << 3));
            ACC8(vv);
        }
    }
    int selfhalf = (node < NHALF) ? 0 : 1;
    if (selfhalf == half) {
        uint4 vs = *(const uint4*)(T + (size_t)node * DIM + (q << 3));
        ACC8(vs);
    }
    __half* P = half ? P1 : P0;
    f16x8 hv;
    hv[0] = (_Float16)a0; hv[1] = (_Float16)a1;
    hv[2] = (_Float16)a2; hv[3] = (_Float16)a3;
    hv[4] = (_Float16)a4; hv[5] = (_Float16)a5;
    hv[6] = (_Float16)a6; hv[7] = (_Float16)a7;
    *(f16x8*)(P + (size_t)node * DIM + (q << 3)) = hv;
}

// ---------------- mlp: P0+P1 -> MFMA MLP -> next table; 4 tiles/wave; binned stats ------
#define MLP_TPW 4
__global__ __launch_bounds__(256) void mlp_kernel(const __half* __restrict__ P0,
                                                  const __half* __restrict__ P1,
                                                  const float* __restrict__ degf,
                                                  const __half* __restrict__ blob,
                                                  const float* __restrict__ cwf,
                                                  const float* __restrict__ bias_a,
                                                  const float* __restrict__ bias_b,
                                                  __half* __restrict__ outT,
                                                  float* __restrict__ sbins) {
    __shared__ __align__(16) _Float16 X[4][512];
    int tid = threadIdx.x;
    int wave = tid >> 6;
    int l = tid & 63;
    int d0 = l & 15, kg = l >> 4;
    int tbase = (blockIdx.x * 4 + wave) * MLP_TPW;
    if (tbase >= NTILES) return;

    f16x8 bA0 = *(const f16x8*)(blob + d0 * 32 + kg * 8);
    f16x8 bA1 = *(const f16x8*)(blob + (d0 + 16) * 32 + kg * 8);
    f16x8 bB0 = *(const f16x8*)(blob + 1024 + d0 * 32 + kg * 8);
    f16x8 bB1 = *(const f16x8*)(blob + 1024 + (d0 + 16) * 32 + kg * 8);
    float cw0 = cwf[d0], cw1 = cwf[d0 + 16];
    float ba0 = bias_a[d0], ba1 = bias_a[d0 + 16];
    float bb0 = bias_b[d0], bb1 = bias_b[d0 + 16];
    float s0 = 0.f, ss0 = 0.f, s1 = 0.f, ss1 = 0.f;

    #pragma unroll
    for (int it = 0; it < MLP_TPW; ++it) {
        int tile = tbase + it;
        if (tile >= NTILES) break;
        int tb = tile * 16;
        f16x8 v0 = *(const f16x8*)(P0 + (size_t)(tb + d0) * DIM + kg * 8);
        f16x8 v1 = *(const f16x8*)(P1 + (size_t)(tb + d0) * DIM + kg * 8);
        f16x8 af = v0 + v1;
        f32x4 degv = *(const f32x4*)(degf + tb + kg * 4);

        f32x4 c0 = {ba0, ba0, ba0, ba0};
        f32x4 c1 = {ba1, ba1, ba1, ba1};
        c0 = __builtin_amdgcn_mfma_f32_16x16x32_f16(af, bA0, c0, 0, 0, 0);
        c1 = __builtin_amdgcn_mfma_f32_16x16x32_f16(af, bA1, c1, 0, 0, 0);
        #pragma unroll
        for (int rr = 0; rr < 4; ++rr) {
            float w0 = fmaxf(c0[rr] + degv[rr] * cw0, 0.f);
            float w1 = fmaxf(c1[rr] + degv[rr] * cw1, 0.f);
            int row = kg * 4 + rr;
            X[wave][row * 32 + d0] = (_Float16)w0;
            X[wave][row * 32 + d0 + 16] = (_Float16)w1;
        }
        __builtin_amdgcn_wave_barrier();
        f16x8 af2 = *(f16x8*)&X[wave][d0 * 32 + kg * 8];
        __builtin_amdgcn_wave_barrier();

        f32x4 e0 = {bb0, bb0, bb0, bb0};
        f32x4 e1 = {bb1, bb1, bb1, bb1};
        e0 = __builtin_amdgcn_mfma_f32_16x16x32_f16(af2, bB0, e0, 0, 0, 0);
        e1 = __builtin_amdgcn_mfma_f32_16x16x32_f16(af2, bB1, e1, 0, 0, 0);
        #pragma unroll
        for (int rr = 0; rr < 4; ++rr) {
            float y0 = fmaxf(e0[rr], 0.f);
            float y1 = fmaxf(e1[rr], 0.f);
            s0 += y0; ss0 += y0 * y0;
            s1 += y1; ss1 += y1 * y1;
            int row = kg * 4 + rr;
            X[wave][row * 32 + d0] = (_Float16)y0;
            X[wave][row * 32 + d0 + 16] = (_Float16)y1;
        }
        __builtin_amdgcn_wave_barrier();
        {
            int gg = l >> 2, c = l & 3;
            uint4 vv = *(uint4*)&X[wave][gg * 32 + c * 8];
            *(uint4*)(outT + (size_t)(tb + gg) * DIM + c * 8) = vv;
        }
        __builtin_amdgcn_wave_barrier();
    }
    s0 += __shfl_xor(s0, 16); s0 += __shfl_xor(s0, 32);
    ss0 += __shfl_xor(ss0, 16); ss0 += __shfl_xor(ss0, 32);
    s1 += __shfl_xor(s1, 16); s1 += __shfl_xor(s1, 32);
    ss1 += __shfl_xor(ss1, 16); ss1 += __shfl_xor(ss1, 32);
    if (kg == 0) {
        float* sb = sbins + ((blockIdx.x * 4 + wave) & (SBINS - 1)) * 64;
        atomicAdd(&sb[d0], s0);
        atomicAdd(&sb[DIM + d0], ss0);
        atomicAdd(&sb[d0 + 16], s1);
        atomicAdd(&sb[DIM + d0 + 16], ss1);
    }
}

// ---------------- final BN + global_add_pool (run-length, batch sorted) ----------------
#define POOL_BLOCKS 512
__global__ __launch_bounds__(256) void bn_pool_kernel(const __half* __restrict__ h,
                                                      const float* __restrict__ sbins,
                                                      const float* __restrict__ gamma,
                                                      const float* __restrict__ beta,
                                                      const int* __restrict__ batch,
                                                      float* __restrict__ pooled) {
    __shared__ float st[64];
    int tid = threadIdx.x;
    if (tid < 64) {
        float s = 0.f;
        for (int b = 0; b < SBINS; ++b) s += sbins[b * 64 + tid];
        st[tid] = s;
    }
    __syncthreads();
    int lane = tid & 31;
    int group = tid >> 5;
    float mu = st[lane] * (1.f / N_NODES);
    float var = st[DIM + lane] * (1.f / N_NODES) - mu * mu;
    float inv = rsqrtf(var + BN_EPS);
    float a = gamma[lane] * inv;
    float c = beta[lane] - mu * a;
    const int ngroups = POOL_BLOCKS * 8;
    const int chunk = (N_NODES + ngroups - 1) / ngroups;
    int g = blockIdx.x * 8 + group;
    int start = g * chunk;
    if (start >= N_NODES) return;
    int end = start + chunk; if (end > N_NODES) end = N_NODES;
    int cur = batch[start];
    float s = 0.f;
    for (int node = start; node < end; ++node) {
        float v = __half2float(h[(size_t)node * DIM + lane]) * a + c;
        int bg = batch[node];
        if (bg != cur) {
            atomicAdd(&pooled[cur * DIM + lane], s);
            s = 0.f;
            cur = bg;
        }
        s += v;
    }
    atomicAdd(&pooled[cur * DIM + lane], s);
}

// ---------------- out = relu(pooled @ Wfc + bfc) ----------------
__global__ __launch_bounds__(256) void fc_kernel(const float* __restrict__ pooled,
                                                 const float* __restrict__ Wfc,
                                                 const float* __restrict__ bfc,
                                                 float* __restrict__ out) {
    __shared__ float Wl[DIM * OUT_DIM];
    for (int i = threadIdx.x; i < DIM * OUT_DIM; i += blockDim.x) Wl[i] = Wfc[i];
    __syncthreads();
    int idx = blockIdx.x * blockDim.x + threadIdx.x;
    int stride = gridDim.x * blockDim.x;
    for (; idx < N_GRAPHS * OUT_DIM; idx += stride) {
        int g = idx >> 7;
        int o = idx & 127;
        float acc = bfc[o];
        #pragma unroll
        for (int k = 0; k < DIM; ++k)
            acc += pooled[g * DIM + k] * Wl[k * OUT_DIM + o];
        out[idx] = fmaxf(acc, 0.f);
    }
}

extern "C" void kernel_launch(void* const* d_in, const int* in_sizes, int n_in,
                              void* d_out, int out_size, void* d_ws, size_t ws_size,
                              hipStream_t stream) {
    const float* x   = (const float*)d_in[0];
    const int* eidx  = (const int*)d_in[1];
    const int* src   = eidx;
    const int* dst   = eidx + N_EDGES;
    const int* batch = (const int*)d_in[2];
    const float* W1a = (const float*)d_in[3];
    const float* b1a = (const float*)d_in[4];
    const float* W1b = (const float*)d_in[5];
    const float* b1b = (const float*)d_in[6];
    const float* Wa  = (const float*)d_in[7];
    const float* ba  = (const float*)d_in[8];
    const float* Wb  = (const float*)d_in[9];
    const float* bb  = (const float*)d_in[10];
    const float* gamma = (const float*)d_in[11];
    const float* beta  = (const float*)d_in[12];
    const float* Wfc = (const float*)d_in[13];
    const float* bfc = (const float*)d_in[14];
    float* out = (float*)d_out;

    const size_t TSZ = (size_t)N_NODES * DIM;                // 3.2M halfs = 6.4MB
    __half* TA = (__half*)d_ws;                              // 6.4MB
    __half* TB = TA + TSZ;                                   // 6.4MB
    __half* P0 = TB + TSZ;                                   // 6.4MB
    __half* P1 = P0 + TSZ;                                   // 6.4MB
    float* degf   = (float*)(P1 + TSZ);                      // 400KB
    float* sbins  = degf + N_NODES;                          // 5 * SBINS * 64
    float* pooled = sbins + 5 * SBINS * 64;                  // 256KB
    float* cwf    = pooled + N_GRAPHS * DIM;                 // 5*32
    __half* blobs = (__half*)(cwf + 5 * 32);                 // 5*2048 halfs
    __half* blob1 = blobs + 5 * 2048;                        // 3072 halfs
    int* csr      = (int*)(blob1 + 6 * 512);                 // 12.8MB
    int* rowst    = csr + N_EDGES;                           // N_NODES+1
    int* rowmid   = rowst + N_NODES + 1;                     // N_NODES
    int* bcnt     = rowmid + N_NODES;
    int* bstart   = bcnt + 256;
    int* qcnt     = bstart + NB + 1;                         // NB*NSUB*BSIZE
    int* bhist    = qcnt + NB * NSUB * BSIZE;                // NCH*256 = 800KB

    // aliases (dead before hosts' first use)
    int* epk             = (int*)TA;              // 12.8MB packed edges over TA+TB
    int* qbase0          = (int*)P1;              // 1.6MB in P1
    int* qbase1          = qbase0 + NB * NSUB * BSIZE;  // 1.6MB in P1

    hipMemsetAsync(sbins, 0, (5 * SBINS * 64 + N_GRAPHS * DIM) * sizeof(float), stream);

    bucket_hist_kernel<<<NCH, 256, 0, stream>>>(dst, bhist);
    col_scan_kernel<<<NB, 256, 0, stream>>>(bhist, bcnt);
    bucket_scan_kernel<<<1, 256, 0, stream>>>(bcnt, bstart, rowst);
    bucket_scatter_kernel<<<NCH, 256, 0, stream>>>(src, dst, bstart, bhist, epk);
    node_count_kernel<<<NB * NSUB, 256, 0, stream>>>(bstart, epk, qcnt);
    node_scan_kernel<<<NB, 256, 0, stream>>>(bstart, qcnt, qbase0, qbase1, rowst, rowmid, degf);
    node_scatter_kernel<<<NB * NR, 256, 0, stream>>>(bstart, epk, qbase0, qbase1, csr);

    prep0_kernel<<<1, 1024, 0, stream>>>(W1a, W1b, blob1, blobs, cwf);
    transform1_kernel<<<(NTILES + 3) / 4, 256, 0, stream>>>(x, blob1, TA);

    const __half* in = TA;
    __half* o = TB;
    const int MLP_GRID = (NTILES + 4 * MLP_TPW - 1) / (4 * MLP_TPW);

    // layer 1
    agg_pass_kernel<<<AGG_BLOCKS, 256, 0, stream>>>(in, rowst, rowmid, csr, P0, P1);
    mlp_kernel<<<MLP_GRID, 256, 0, stream>>>(P0, P1, degf, blobs, cwf, b1a, b1b, o, sbins);
    { const __half* t = in; in = o; o = (__half*)t; }

    for (int i = 0; i < 4; ++i) {
        __half* blob_i = blobs + (i + 1) * 2048;
        float* cwf_i = cwf + (i + 1) * 32;
        prep_kernel<<<1, 1024, 0, stream>>>(sbins + i * SBINS * 64, gamma + i * DIM, beta + i * DIM,
                                            Wa + i * DIM * DIM, Wb + i * DIM * DIM, blob_i, cwf_i);
        agg_pass_kernel<<<AGG_BLOCKS, 256, 0, stream>>>(in, rowst, rowmid, csr, P0, P1);
        mlp_kernel<<<MLP_GRID, 256, 0, stream>>>(P0, P1, degf, blob_i, cwf_i,
                                                 ba + i * DIM, bb + i * DIM, o,
                                                 sbins + (i + 1) * SBINS * 64);
        { const __half* t = in; in = o; o = (__half*)t; }
    }

    bn_pool_kernel<<<POOL_BLOCKS, 256, 0, stream>>>(in, sbins + 4 * SBINS * 64,
                                                    gamma + 4 * DIM, beta + 4 * DIM, batch, pooled);
    fc_kernel<<<1024, 256, 0, stream>>>(pooled, Wfc, bfc, out);
}